// Round 2
// baseline (666.765 us; speedup 1.0000x reference)
//
#include <hip/hip_runtime.h>
#include <stdint.h>

// Problem dims
#define T_TOK 4096
#define DMODEL 2048
#define HDIM 1408
#define NEXP 8
#define TOPK 2

// GEMM tile
#define BM 128
#define BN 128
#define BK 64
#define MAX_TILES ((T_TOK * TOPK) / BM + NEXP) // 72

typedef unsigned short u16;
typedef __bf16 bf16x8 __attribute__((ext_vector_type(8)));
typedef float f32x4 __attribute__((ext_vector_type(4)));

__device__ __forceinline__ u16 f2bf(float f) {
  union { float f; uint32_t u; } v; v.f = f;
  uint32_t r = (v.u + 0x7FFFu + ((v.u >> 16) & 1u)) >> 16;
  return (u16)r;
}

__device__ __forceinline__ void gll16(const void* g, void* l) {
  __builtin_amdgcn_global_load_lds(
      (__attribute__((address_space(1))) void*)(uintptr_t)g,
      (__attribute__((address_space(3))) void*)l, 16, 0, 0);
}

// ---- fp32 -> bf16 conversion of x, w1, w2 (one pass, vectorized 8/thread) ----
__global__ __launch_bounds__(256) void convert_all(
    const float* __restrict__ x, const float* __restrict__ w1,
    const float* __restrict__ w2, u16* __restrict__ xb,
    u16* __restrict__ w1b, u16* __restrict__ w2b) {
  const long c0 = (long)T_TOK * DMODEL / 8;
  const long c1 = (long)NEXP * 2 * HDIM * DMODEL / 8;
  const long c2 = (long)NEXP * DMODEL * HDIM / 8;
  const long total = c0 + c1 + c2;
  const long stride = (long)gridDim.x * blockDim.x;
  for (long i = blockIdx.x * (long)blockDim.x + threadIdx.x; i < total; i += stride) {
    const float* s; u16* d; long j;
    if (i < c0)            { s = x;  d = xb;  j = i; }
    else if (i < c0 + c1)  { s = w1; d = w1b; j = i - c0; }
    else                   { s = w2; d = w2b; j = i - c0 - c1; }
    const float4* sp = (const float4*)s + j * 2;
    float4 v0 = sp[0], v1 = sp[1];
    union { u16 us[8]; uint4 u4; } o;
    o.us[0] = f2bf(v0.x); o.us[1] = f2bf(v0.y); o.us[2] = f2bf(v0.z); o.us[3] = f2bf(v0.w);
    o.us[4] = f2bf(v1.x); o.us[5] = f2bf(v1.y); o.us[6] = f2bf(v1.z); o.us[7] = f2bf(v1.w);
    *((uint4*)(d + j * 8)) = o.u4;
  }
}

// ---- routing: per-expert list of rids (rid = t*K + k) ----
__global__ void route_kernel(const int* __restrict__ idx, int* __restrict__ cnt,
                             int* __restrict__ perm) {
  int i = blockIdx.x * blockDim.x + threadIdx.x;
  if (i < T_TOK * TOPK) {
    int e = idx[i];
    int p = atomicAdd(&cnt[e], 1);
    perm[e * T_TOK + p] = i;
  }
}

__global__ void tilemap_kernel(const int* __restrict__ cnt, int* __restrict__ tmap,
                               int* __restrict__ ntp) {
  if (threadIdx.x == 0 && blockIdx.x == 0) {
    int nt = 0;
    for (int e = 0; e < NEXP; ++e) {
      int n = cnt[e];
      for (int r = 0; r < n; r += BM) tmap[nt++] = (e << 16) | r;
    }
    *ntp = nt;
  }
}

// ---- grouped GEMM ----
// MODE 0: A=xb[T,D] gathered by rid>>1, B=w1b[E,2H,D]; computes u and g tiles,
//         epilogue act[rid][col] = u*silu(g) (bf16)
// MODE 1: A=act[T*K,H] gathered by rid, B=w2b[E,D,H];
//         epilogue pairs[rid][col] = acc * weights[rid] (fp32)
template <int MODE>
__global__ __launch_bounds__(256, 2) void moe_gemm(
    const u16* __restrict__ A, const u16* __restrict__ Bw,
    const float* __restrict__ wts, const int* __restrict__ perm,
    const int* __restrict__ cnt, const int* __restrict__ tmap,
    const int* __restrict__ ntp, u16* __restrict__ act,
    float* __restrict__ pairs) {
  constexpr int KD = (MODE == 0) ? DMODEL : HDIM;
  if ((int)blockIdx.x >= *ntp) return;
  const int tm = tmap[blockIdx.x];
  const int e = tm >> 16, r0 = tm & 0xFFFF;
  const int ne = cnt[e];

  __shared__ int rid_s[BM];
  __shared__ __align__(16) u16 Asm[BM][BK];
  __shared__ __align__(16) u16 Bu[BM][BK];
  __shared__ __align__(16) u16 Bg[(MODE == 0) ? BM : 1][BK];

  const int tid = threadIdx.x;
  if (tid < BM) {
    int ii = r0 + tid;
    rid_s[tid] = perm[e * T_TOK + (ii < ne ? ii : ne - 1)];
  }
  __syncthreads();

  const int wave = tid >> 6;
  const int lane = tid & 63;
  const int wr = wave >> 1, wc = wave & 1;

  // staging source pointers (4 chunks of 16B per thread per tile)
  const int col8 = (tid & 7) * 8;
  const u16* aptr[4];
  const u16* buptr[4];
  const u16* bgptr[4];
#pragma unroll
  for (int r = 0; r < 4; ++r) {
    int row = (tid >> 3) + r * 32;
    int rid = rid_s[row];
    long arow = (MODE == 0) ? (long)(rid >> 1) : (long)rid;
    aptr[r] = A + arow * KD + col8;
    if constexpr (MODE == 0) {
      buptr[r] = Bw + ((long)e * 2 * HDIM + blockIdx.y * BN + row) * KD + col8;
      bgptr[r] = Bw + ((long)e * 2 * HDIM + HDIM + blockIdx.y * BN + row) * KD + col8;
    } else {
      buptr[r] = Bw + ((long)e * DMODEL + blockIdx.y * BN + row) * KD + col8;
    }
  }
  char* aldst = (char*)(&Asm[0][0]) + wave * 1024;
  char* buldst = (char*)(&Bu[0][0]) + wave * 1024;
  char* bgldst = (char*)(&Bg[0][0]) + wave * 1024;

  f32x4 accU[4][4] = {};
  f32x4 accG[4][4] = {};

  for (int k0 = 0; k0 < KD; k0 += BK) {
    __syncthreads(); // previous compute done before overwriting LDS
#pragma unroll
    for (int r = 0; r < 4; ++r) {
      gll16(aptr[r] + k0, aldst + r * 4096);
      gll16(buptr[r] + k0, buldst + r * 4096);
      if constexpr (MODE == 0) gll16(bgptr[r] + k0, bgldst + r * 4096);
    }
    __syncthreads(); // staging drained (compiler emits vmcnt(0) before barrier)
#pragma unroll
    for (int ks = 0; ks < 2; ++ks) {
      const int koff = ks * 32 + (lane >> 4) * 8;
      const int rsel = lane & 15;
      bf16x8 a[4], bu[4], bg[4];
#pragma unroll
      for (int m = 0; m < 4; ++m)
        a[m] = *(const bf16x8*)&Asm[wr * 64 + m * 16 + rsel][koff];
#pragma unroll
      for (int n = 0; n < 4; ++n) {
        bu[n] = *(const bf16x8*)&Bu[wc * 64 + n * 16 + rsel][koff];
        if constexpr (MODE == 0)
          bg[n] = *(const bf16x8*)&Bg[wc * 64 + n * 16 + rsel][koff];
      }
#pragma unroll
      for (int m = 0; m < 4; ++m)
#pragma unroll
        for (int n = 0; n < 4; ++n) {
          accU[m][n] = __builtin_amdgcn_mfma_f32_16x16x32_bf16(a[m], bu[n], accU[m][n], 0, 0, 0);
          if constexpr (MODE == 0)
            accG[m][n] = __builtin_amdgcn_mfma_f32_16x16x32_bf16(a[m], bg[n], accG[m][n], 0, 0, 0);
        }
    }
  }

  // epilogue: C/D layout col = lane&15, row = (lane>>4)*4 + reg  [m89-verified]
  const int cbase = blockIdx.y * BN + wc * 64;
#pragma unroll
  for (int m = 0; m < 4; ++m) {
    const int rb = wr * 64 + m * 16 + (lane >> 4) * 4;
#pragma unroll
    for (int rg = 0; rg < 4; ++rg) {
      const int rloc = rb + rg;
      if (r0 + rloc >= ne) continue; // padded row
      const int rid = rid_s[rloc];
      if constexpr (MODE == 0) {
#pragma unroll
        for (int n = 0; n < 4; ++n) {
          const int col = cbase + n * 16 + (lane & 15);
          float g = accG[m][n][rg];
          float u = accU[m][n][rg];
          float val = u * (g / (1.f + __expf(-g)));
          act[(long)rid * HDIM + col] = f2bf(val);
        }
      } else {
        const float w = wts[rid];
#pragma unroll
        for (int n = 0; n < 4; ++n) {
          const int col = cbase + n * 16 + (lane & 15);
          pairs[(long)rid * DMODEL + col] = accU[m][n][rg] * w;
        }
      }
    }
  }
}

// ---- y[t] = pairs[2t] + pairs[2t+1] ----
__global__ __launch_bounds__(256) void reduce_pairs(const float* __restrict__ pairs,
                                                    float* __restrict__ y) {
  const long total = (long)T_TOK * DMODEL / 4;
  const long stride = (long)gridDim.x * blockDim.x;
  for (long i = blockIdx.x * (long)blockDim.x + threadIdx.x; i < total; i += stride) {
    long t = (i * 4) / DMODEL;
    long d = (i * 4) % DMODEL;
    float4 a = *(const float4*)(pairs + (2 * t) * DMODEL + d);
    float4 b = *(const float4*)(pairs + (2 * t + 1) * DMODEL + d);
    float4 r;
    r.x = a.x + b.x; r.y = a.y + b.y; r.z = a.z + b.z; r.w = a.w + b.w;
    *(float4*)(y + t * DMODEL + d) = r;
  }
}

extern "C" void kernel_launch(void* const* d_in, const int* in_sizes, int n_in,
                              void* d_out, int out_size, void* d_ws, size_t ws_size,
                              hipStream_t stream) {
  const float* x = (const float*)d_in[0];
  const float* wts = (const float*)d_in[1];
  const int* idx = (const int*)d_in[2];
  const float* w1 = (const float*)d_in[3];
  const float* w2 = (const float*)d_in[4];
  float* y = (float*)d_out;

  char* ws = (char*)d_ws;
  size_t off = 0;
  int* cnt = (int*)(ws + off); off += 256;
  int* ntp = (int*)(ws + off); off += 256;
  int* tmap = (int*)(ws + off); off += 1024;
  int* perm = (int*)(ws + off); off += (size_t)NEXP * T_TOK * 4;
  off = (off + 255) & ~(size_t)255;
  size_t xb_off = off;
  u16* xb = (u16*)(ws + off);  off += (size_t)T_TOK * DMODEL * 2;             // 16.8 MB
  u16* w1b = (u16*)(ws + off); off += (size_t)NEXP * 2 * HDIM * DMODEL * 2;   // 92.3 MB
  u16* w2b = (u16*)(ws + off); off += (size_t)NEXP * DMODEL * HDIM * 2;       // 46.1 MB
  u16* act = (u16*)(ws + off); off += (size_t)T_TOK * TOPK * HDIM * 2;        // 23.1 MB
  // pairs aliases xb+w1b (both dead once GEMM1 finished): 67.1 MB <= 109 MB
  float* pairs = (float*)(ws + xb_off);

  hipMemsetAsync(cnt, 0, 256, stream);
  convert_all<<<2048, 256, 0, stream>>>(x, w1, w2, xb, w1b, w2b);
  route_kernel<<<(T_TOK * TOPK + 255) / 256, 256, 0, stream>>>(idx, cnt, perm);
  tilemap_kernel<<<1, 64, 0, stream>>>(cnt, tmap, ntp);
  moe_gemm<0><<<dim3(MAX_TILES, HDIM / BN), 256, 0, stream>>>(
      xb, w1b, wts, perm, cnt, tmap, ntp, act, nullptr);
  moe_gemm<1><<<dim3(MAX_TILES, DMODEL / BN), 256, 0, stream>>>(
      act, w2b, wts, perm, cnt, tmap, ntp, nullptr, pairs);
  reduce_pairs<<<2048, 256, 0, stream>>>(pairs, y);
}

// Round 8
// 642.127 us; speedup vs baseline: 1.0384x; 1.0384x over previous
//
#include <hip/hip_runtime.h>
#include <stdint.h>

// Problem dims
#define T_TOK 4096
#define DMODEL 2048
#define HDIM 1408
#define NEXP 8
#define TOPK 2

// GEMM tile (256x256, BK=32, 512 threads = 8 waves as 2x4)
#define BM 256
#define BN 256
#define BK 32
#define MAX_TILES (T_TOK * TOPK / BM + NEXP) // 40
#define SMEM_BYTES (131072 + 1024)           // 4 ring buffers (4x32KB) + rid_s

typedef unsigned short u16;
typedef __bf16 bf16x8 __attribute__((ext_vector_type(8)));
typedef float f32x4 __attribute__((ext_vector_type(4)));

__device__ __forceinline__ u16 f2bf(float f) {
  union { float f; uint32_t u; } v; v.f = f;
  uint32_t r = (v.u + 0x7FFFu + ((v.u >> 16) & 1u)) >> 16;
  return (u16)r;
}

__device__ __forceinline__ void gll16(const void* g, void* l) {
  __builtin_amdgcn_global_load_lds(
      (__attribute__((address_space(1))) void*)(uintptr_t)g,
      (__attribute__((address_space(3))) void*)l, 16, 0, 0);
}

// ---- fp32 -> bf16 conversion of x, w1, w2 ----
__global__ __launch_bounds__(256) void convert_all(
    const float* __restrict__ x, const float* __restrict__ w1,
    const float* __restrict__ w2, u16* __restrict__ xb,
    u16* __restrict__ w1b, u16* __restrict__ w2b) {
  const long c0 = (long)T_TOK * DMODEL / 8;
  const long c1 = (long)NEXP * 2 * HDIM * DMODEL / 8;
  const long c2 = (long)NEXP * DMODEL * HDIM / 8;
  const long total = c0 + c1 + c2;
  const long stride = (long)gridDim.x * blockDim.x;
  for (long i = blockIdx.x * (long)blockDim.x + threadIdx.x; i < total; i += stride) {
    const float* s; u16* d; long j;
    if (i < c0)            { s = x;  d = xb;  j = i; }
    else if (i < c0 + c1)  { s = w1; d = w1b; j = i - c0; }
    else                   { s = w2; d = w2b; j = i - c0 - c1; }
    const float4* sp = (const float4*)s + j * 2;
    float4 v0 = sp[0], v1 = sp[1];
    union { u16 us[8]; uint4 u4; } o;
    o.us[0] = f2bf(v0.x); o.us[1] = f2bf(v0.y); o.us[2] = f2bf(v0.z); o.us[3] = f2bf(v0.w);
    o.us[4] = f2bf(v1.x); o.us[5] = f2bf(v1.y); o.us[6] = f2bf(v1.z); o.us[7] = f2bf(v1.w);
    *((uint4*)(d + j * 8)) = o.u4;
  }
}

// ---- routing ----
__global__ void route_kernel(const int* __restrict__ idx, int* __restrict__ cnt,
                             int* __restrict__ perm) {
  int i = blockIdx.x * blockDim.x + threadIdx.x;
  if (i < T_TOK * TOPK) {
    int e = idx[i];
    int p = atomicAdd(&cnt[e], 1);
    perm[e * T_TOK + p] = i;
  }
}

__global__ void tilemap_kernel(const int* __restrict__ cnt, int* __restrict__ tmap,
                               int* __restrict__ ntp) {
  if (threadIdx.x == 0 && blockIdx.x == 0) {
    int nt = 0;
    for (int e = 0; e < NEXP; ++e) {
      int n = cnt[e];
      for (int r = 0; r < n; r += BM) tmap[nt++] = (e << 16) | r;
    }
    *ntp = nt;
  }
}

// ================= grouped GEMM, 8-wave 256x256, 4-deep pipelined ring =======
// LDS ring: buf b at smem + b*32768; A tile [256][32] bf16 at +0, B at +16384.
// XOR swizzle (T2): LDS[row][s] holds G[row][s ^ ((row>>1)&3)] (16B slots).
// Schedule: tile t computed in phases (t,0),(t,1); its 4 loads (2 A + 2 B per
// thread) issued during tile t-3's two phases; vmcnt(8) at phase (t-1,1)
// guarantees arrival (8 loads issued after tile t's last). Tail peels 3 tiles
// with vmcnt(4)/vmcnt(0)/none. Raw s_barrier only (no vmcnt(0) drain).

template <int H, int VMN>
__device__ __forceinline__ void phase_core(const char* bc, const int (&aoffR)[8],
                                           const int (&boffR)[4], f32x4 (&acc)[8][4]) {
  bf16x8 a_[4], b_[4];
#pragma unroll
  for (int m = 0; m < 4; ++m) a_[m] = *(const bf16x8*)(bc + aoffR[H * 4 + m]);
#pragma unroll
  for (int n = 0; n < 4; ++n) b_[n] = *(const bf16x8*)(bc + boffR[n]);
  if constexpr (VMN == 8) {
    asm volatile("s_waitcnt vmcnt(8)" ::: "memory");
    __builtin_amdgcn_sched_barrier(0);
  } else if constexpr (VMN == 4) {
    asm volatile("s_waitcnt vmcnt(4)" ::: "memory");
    __builtin_amdgcn_sched_barrier(0);
  } else if constexpr (VMN == 0) {
    asm volatile("s_waitcnt vmcnt(0)" ::: "memory");
    __builtin_amdgcn_sched_barrier(0);
  }
  __builtin_amdgcn_s_barrier();
  __builtin_amdgcn_s_setprio(1);
#pragma unroll
  for (int m = 0; m < 4; ++m)
#pragma unroll
    for (int n = 0; n < 4; ++n)
      acc[H * 4 + m][n] = __builtin_amdgcn_mfma_f32_16x16x32_bf16(
          a_[m], b_[n], acc[H * 4 + m][n], 0, 0, 0);
  __builtin_amdgcn_s_setprio(0);
  __builtin_amdgcn_s_barrier();
}

// MODE 0: A=xb[T,D] gathered by rid>>1; B-rows remapped so one block covers
//         128 u-cols + 128 g-cols of the same range; epilogue fuses u*silu(g)
//         via LDS exchange -> act[rid][HDIM] bf16.
// MODE 1: A=act[T*K,H] by rid; B=w2b; epilogue pairs[rid][D] = acc*wts (f32).
template <int MODE>
__global__ __launch_bounds__(512, 2) void moe_gemm(
    const u16* __restrict__ A, const u16* __restrict__ Bw,
    const float* __restrict__ wts, const int* __restrict__ perm,
    const int* __restrict__ cnt, const int* __restrict__ tmap,
    const int* __restrict__ ntp, u16* __restrict__ act,
    float* __restrict__ pairs) {
  constexpr int KD = (MODE == 0) ? DMODEL : HDIM;
  constexpr int NT = KD / BK; // 64 / 44, both >= 4
  extern __shared__ char smem[];
  int* rid_s = (int*)(smem + 131072);

  if ((int)blockIdx.x >= *ntp) return;
  const int tm = tmap[blockIdx.x];
  const int e = tm >> 16, r0 = tm & 0xFFFF;
  const int ne = cnt[e];
  const int tid = threadIdx.x;
  if (tid < BM) {
    int ii = r0 + tid;
    rid_s[tid] = perm[e * T_TOK + (ii < ne ? ii : ne - 1)];
  }
  __syncthreads();

  const int w = tid >> 6, l = tid & 63;
  const int wr = w >> 2, wc = w & 3;
  const int yb = blockIdx.y;

  // ---- staging: wave w owns A chunks {2w,2w+1} and B chunks {2w,2w+1}
  // chunk c = 16 rows; lane l -> row 16c + (l>>2), slot l&3.
  // global source slot = (l&3) ^ ((row>>1)&3) = (l&3) ^ ((l>>3)&3).
  const int ar1 = 32 * w + (l >> 2);
  const int ar2 = ar1 + 16;
  const int sslot = ((l & 3) ^ ((l >> 3) & 3)) * 8; // element offset
  long arow1, arow2;
  {
    int rid1 = rid_s[ar1], rid2 = rid_s[ar2];
    arow1 = (MODE == 0) ? (rid1 >> 1) : rid1;
    arow2 = (MODE == 0) ? (rid2 >> 1) : rid2;
  }
  const u16* aptr1 = A + arow1 * KD + sslot;
  const u16* aptr2 = A + arow2 * KD + sslot;
  long brow1, brow2;
  if constexpr (MODE == 0) {
    brow1 = (long)e * (2 * HDIM) + (ar1 < 128 ? yb * 128 + ar1 : HDIM + yb * 128 + ar1 - 128);
    brow2 = (long)e * (2 * HDIM) + (ar2 < 128 ? yb * 128 + ar2 : HDIM + yb * 128 + ar2 - 128);
  } else {
    brow1 = (long)e * DMODEL + yb * BN + ar1;
    brow2 = (long)e * DMODEL + yb * BN + ar2;
  }
  const u16* bptr1 = Bw + brow1 * KD + sslot;
  const u16* bptr2 = Bw + brow2 * KD + sslot;
  const int aoffL1 = 2 * w * 1024, aoffL2 = aoffL1 + 1024;
  const int boffL1 = 16384 + 2 * w * 1024, boffL2 = boffL1 + 1024;

  // ---- ds_read fragment offsets (swizzled): k-slot (l>>4) ^ ((row>>1)&3)
  const int swz = ((l >> 4) ^ ((l >> 1) & 3)) * 16;
  int aoffR[8];
#pragma unroll
  for (int h = 0; h < 2; ++h)
#pragma unroll
    for (int m = 0; m < 4; ++m)
      aoffR[h * 4 + m] = (wr * 128 + h * 64 + m * 16 + (l & 15)) * 64 + swz;
  int boffR[4];
#pragma unroll
  for (int n = 0; n < 4; ++n)
    boffR[n] = 16384 + (wc * 64 + n * 16 + (l & 15)) * 64 + swz;

  f32x4 acc[8][4] = {};

  // ---- prologue: stage tiles 0,1,2 (order A,A,B,B per tile)
#pragma unroll
  for (int tt = 0; tt < 3; ++tt) {
    char* sb = smem + tt * 32768;
    const size_t kq = (size_t)tt * BK;
    gll16(aptr1 + kq, sb + aoffL1);
    gll16(aptr2 + kq, sb + aoffL2);
    gll16(bptr1 + kq, sb + boffL1);
    gll16(bptr2 + kq, sb + boffL2);
  }
  asm volatile("s_waitcnt vmcnt(8)" ::: "memory"); // tile 0 landed
  __builtin_amdgcn_sched_barrier(0);
  __builtin_amdgcn_s_barrier();

  // ---- main loop: tiles 0..NT-4, staging tile t+3
  for (int t = 0; t <= NT - 4; ++t) {
    const char* bufc = smem + (t & 3) * 32768;
    char* sb = smem + ((t + 3) & 3) * 32768;
    const size_t kq = (size_t)(t + 3) * BK;
    gll16(aptr1 + kq, sb + aoffL1);
    gll16(aptr2 + kq, sb + aoffL2);
    phase_core<0, -1>(bufc, aoffR, boffR, acc);
    gll16(bptr1 + kq, sb + boffL1);
    gll16(bptr2 + kq, sb + boffL2);
    phase_core<1, 8>(bufc, aoffR, boffR, acc); // tile t+1 guaranteed landed
  }
  // ---- tail: tiles NT-3, NT-2, NT-1 (no staging; decreasing waits)
  {
    const char* bufc = smem + ((NT - 3) & 3) * 32768;
    phase_core<0, -1>(bufc, aoffR, boffR, acc);
    phase_core<1, 4>(bufc, aoffR, boffR, acc);
  }
  {
    const char* bufc = smem + ((NT - 2) & 3) * 32768;
    phase_core<0, -1>(bufc, aoffR, boffR, acc);
    phase_core<1, 0>(bufc, aoffR, boffR, acc);
  }
  {
    const char* bufc = smem + ((NT - 1) & 3) * 32768;
    phase_core<0, -1>(bufc, aoffR, boffR, acc);
    phase_core<1, -1>(bufc, aoffR, boffR, acc);
  }

  // ---- epilogue. C/D layout: col = lane&15 (B-row), row = (lane>>4)*4+reg.
  if constexpr (MODE == 0) {
    // waves wc>=2 hold gate cols; exchange via LDS (aliases dead ring bufs)
    float* g_lds = (float*)smem;
    if (wc >= 2) {
      const int cl = (wc - 2) * 64;
#pragma unroll
      for (int mm = 0; mm < 8; ++mm)
#pragma unroll
        for (int n = 0; n < 4; ++n)
#pragma unroll
          for (int rg = 0; rg < 4; ++rg) {
            int row = wr * 128 + mm * 16 + (l >> 4) * 4 + rg;
            g_lds[row * 128 + cl + n * 16 + (l & 15)] = acc[mm][n][rg];
          }
    }
    __syncthreads();
    if (wc < 2) {
      const int cl = wc * 64;
#pragma unroll
      for (int mm = 0; mm < 8; ++mm) {
        const int rb = wr * 128 + mm * 16 + (l >> 4) * 4;
#pragma unroll
        for (int rg = 0; rg < 4; ++rg) {
          const int rloc = rb + rg;
          if (r0 + rloc >= ne) continue;
          const int rid = rid_s[rloc];
#pragma unroll
          for (int n = 0; n < 4; ++n) {
            const int col = cl + n * 16 + (l & 15);
            float g = g_lds[rloc * 128 + col];
            float u = acc[mm][n][rg];
            float val = u * (g / (1.f + __expf(-g)));
            act[(size_t)rid * HDIM + yb * 128 + col] = f2bf(val);
          }
        }
      }
    }
  } else {
#pragma unroll
    for (int mm = 0; mm < 8; ++mm) {
      const int rb = wr * 128 + mm * 16 + (l >> 4) * 4;
#pragma unroll
      for (int rg = 0; rg < 4; ++rg) {
        const int rloc = rb + rg;
        if (r0 + rloc >= ne) continue;
        const int rid = rid_s[rloc];
        const float wt = wts[rid];
#pragma unroll
        for (int n = 0; n < 4; ++n) {
          const int col = yb * BN + wc * 64 + n * 16 + (l & 15);
          pairs[(size_t)rid * DMODEL + col] = acc[mm][n][rg] * wt;
        }
      }
    }
  }
}

// ---- y[t] = pairs[2t] + pairs[2t+1] ----
__global__ __launch_bounds__(256) void reduce_pairs(const float* __restrict__ pairs,
                                                    float* __restrict__ y) {
  const long total = (long)T_TOK * DMODEL / 4;
  const long stride = (long)gridDim.x * blockDim.x;
  for (long i = blockIdx.x * (long)blockDim.x + threadIdx.x; i < total; i += stride) {
    long t = (i * 4) / DMODEL;
    long d = (i * 4) % DMODEL;
    float4 a = *(const float4*)(pairs + (2 * t) * DMODEL + d);
    float4 b = *(const float4*)(pairs + (2 * t + 1) * DMODEL + d);
    float4 r;
    r.x = a.x + b.x; r.y = a.y + b.y; r.z = a.z + b.z; r.w = a.w + b.w;
    *(float4*)(y + t * DMODEL + d) = r;
  }
}

extern "C" void kernel_launch(void* const* d_in, const int* in_sizes, int n_in,
                              void* d_out, int out_size, void* d_ws, size_t ws_size,
                              hipStream_t stream) {
  const float* x = (const float*)d_in[0];
  const float* wts = (const float*)d_in[1];
  const int* idx = (const int*)d_in[2];
  const float* w1 = (const float*)d_in[3];
  const float* w2 = (const float*)d_in[4];
  float* y = (float*)d_out;

  char* ws = (char*)d_ws;
  size_t off = 0;
  int* cnt = (int*)(ws + off); off += 256;
  int* ntp = (int*)(ws + off); off += 256;
  int* tmap = (int*)(ws + off); off += 1024;
  int* perm = (int*)(ws + off); off += (size_t)NEXP * T_TOK * 4;
  off = (off + 255) & ~(size_t)255;
  size_t xb_off = off;
  u16* xb = (u16*)(ws + off);  off += (size_t)T_TOK * DMODEL * 2;             // 16.8 MB
  u16* w1b = (u16*)(ws + off); off += (size_t)NEXP * 2 * HDIM * DMODEL * 2;   // 92.3 MB
  u16* w2b = (u16*)(ws + off); off += (size_t)NEXP * DMODEL * HDIM * 2;       // 46.1 MB
  u16* act = (u16*)(ws + off); off += (size_t)T_TOK * TOPK * HDIM * 2;        // 23.1 MB
  // pairs aliases xb+w1b (both dead once GEMM1 finished): 67.1 MB <= 109 MB
  float* pairs = (float*)(ws + xb_off);

  // defensive: allow >64KB dynamic LDS (no-op if already permitted)
  (void)hipFuncSetAttribute((const void*)moe_gemm<0>,
                            hipFuncAttributeMaxDynamicSharedMemorySize, SMEM_BYTES);
  (void)hipFuncSetAttribute((const void*)moe_gemm<1>,
                            hipFuncAttributeMaxDynamicSharedMemorySize, SMEM_BYTES);

  hipMemsetAsync(cnt, 0, 256, stream);
  convert_all<<<2048, 256, 0, stream>>>(x, w1, w2, xb, w1b, w2b);
  route_kernel<<<(T_TOK * TOPK + 255) / 256, 256, 0, stream>>>(idx, cnt, perm);
  tilemap_kernel<<<1, 64, 0, stream>>>(cnt, tmap, ntp);
  moe_gemm<0><<<dim3(MAX_TILES, HDIM / 128), 512, SMEM_BYTES, stream>>>(
      xb, w1b, wts, perm, cnt, tmap, ntp, act, nullptr);
  moe_gemm<1><<<dim3(MAX_TILES, DMODEL / BN), 512, SMEM_BYTES, stream>>>(
      act, w2b, wts, perm, cnt, tmap, ntp, nullptr, pairs);
  reduce_pairs<<<2048, 256, 0, stream>>>(pairs, y);
}

// Round 9
// 617.657 us; speedup vs baseline: 1.0795x; 1.0396x over previous
//
#include <hip/hip_runtime.h>
#include <stdint.h>

// Problem dims
#define T_TOK 4096
#define DMODEL 2048
#define HDIM 1408
#define NEXP 8
#define TOPK 2

// GEMM tile (256x256, BK=32, 512 threads = 8 waves as 2x4)
#define BM 256
#define BN 256
#define BK 32
#define MAX_TILES (T_TOK * TOPK / BM + NEXP) // 40
#define SMEM_BYTES (131072 + 1024)           // 4 ring buffers (4x32KB) + rid_s

typedef unsigned short u16;
typedef __bf16 bf16x8 __attribute__((ext_vector_type(8)));
typedef float f32x4 __attribute__((ext_vector_type(4)));

__device__ __forceinline__ u16 f2bf(float f) {
  union { float f; uint32_t u; } v; v.f = f;
  uint32_t r = (v.u + 0x7FFFu + ((v.u >> 16) & 1u)) >> 16;
  return (u16)r;
}

__device__ __forceinline__ void gll16(const void* g, void* l) {
  __builtin_amdgcn_global_load_lds(
      (__attribute__((address_space(1))) void*)(uintptr_t)g,
      (__attribute__((address_space(3))) void*)l, 16, 0, 0);
}

// ---- fp32 -> bf16 conversion (branch-free, one src/dst per launch) ----
__global__ __launch_bounds__(256) void convert_k(const float* __restrict__ s,
                                                 u16* __restrict__ d, long n8) {
  const long stride = (long)gridDim.x * blockDim.x;
  for (long i = blockIdx.x * (long)blockDim.x + threadIdx.x; i < n8; i += stride) {
    float4 v0 = ((const float4*)s)[2 * i];
    float4 v1 = ((const float4*)s)[2 * i + 1];
    union { u16 us[8]; uint4 u4; } o;
    o.us[0] = f2bf(v0.x); o.us[1] = f2bf(v0.y); o.us[2] = f2bf(v0.z); o.us[3] = f2bf(v0.w);
    o.us[4] = f2bf(v1.x); o.us[5] = f2bf(v1.y); o.us[6] = f2bf(v1.z); o.us[7] = f2bf(v1.w);
    ((uint4*)d)[i] = o.u4;
  }
}

// ---- routing ----
__global__ void route_kernel(const int* __restrict__ idx, int* __restrict__ cnt,
                             int* __restrict__ perm) {
  int i = blockIdx.x * blockDim.x + threadIdx.x;
  if (i < T_TOK * TOPK) {
    int e = idx[i];
    int p = atomicAdd(&cnt[e], 1);
    perm[e * T_TOK + p] = i;
  }
}

__global__ void tilemap_kernel(const int* __restrict__ cnt, int* __restrict__ tmap,
                               int* __restrict__ ntp) {
  if (threadIdx.x == 0 && blockIdx.x == 0) {
    int nt = 0;
    for (int e = 0; e < NEXP; ++e) {
      int n = cnt[e];
      for (int r = 0; r < n; r += BM) tmap[nt++] = (e << 16) | r;
    }
    *ntp = nt;
  }
}

// ========== grouped GEMM, 8-wave 256x256, 4-deep ring, 1 phase/K-tile =======
// LDS ring: buf b at smem + b*32768; A tile [256][32] bf16 at +0, B at +16384.
// XOR swizzle (T2): LDS[row][s] holds G[row][s ^ ((row>>1)&3)] (16B slots).
// Per K-tile t (ONE barrier): {ds_read 12 frags of t; stage t+3 (4 gll);
// 32 MFMA; vmcnt(8) -> tile t+1 landed; s_barrier}. Outstanding after stage
// = 12 (t+1..t+3); vmcnt(8) retires t+1's 4. Tail peels vmcnt(4)/(0)/none.
// This halves LDS reads vs 2-sub-phase (no B re-read) and cuts barriers 4->1.

template <int VMN, bool STG, bool BAR>
__device__ __forceinline__ void ktile(
    const char* bc, char* sb, size_t kq,
    const u16* aptr1, const u16* aptr2, const u16* bptr1, const u16* bptr2,
    int aoffL1, int aoffL2, int boffL1, int boffL2,
    const int (&aoffR)[8], const int (&boffR)[4], f32x4 (&acc)[8][4]) {
  bf16x8 a_[8], b_[4];
#pragma unroll
  for (int m = 0; m < 8; ++m) a_[m] = *(const bf16x8*)(bc + aoffR[m]);
#pragma unroll
  for (int n = 0; n < 4; ++n) b_[n] = *(const bf16x8*)(bc + boffR[n]);
  if constexpr (STG) {
    gll16(aptr1 + kq, sb + aoffL1);
    gll16(aptr2 + kq, sb + aoffL2);
    gll16(bptr1 + kq, sb + boffL1);
    gll16(bptr2 + kq, sb + boffL2);
  }
  __builtin_amdgcn_s_setprio(1);
#pragma unroll
  for (int m = 0; m < 8; ++m)
#pragma unroll
    for (int n = 0; n < 4; ++n)
      acc[m][n] = __builtin_amdgcn_mfma_f32_16x16x32_bf16(a_[m], b_[n], acc[m][n], 0, 0, 0);
  __builtin_amdgcn_s_setprio(0);
  if constexpr (VMN == 8) {
    asm volatile("s_waitcnt vmcnt(8)" ::: "memory");
    __builtin_amdgcn_sched_barrier(0);
  } else if constexpr (VMN == 4) {
    asm volatile("s_waitcnt vmcnt(4)" ::: "memory");
    __builtin_amdgcn_sched_barrier(0);
  } else if constexpr (VMN == 0) {
    asm volatile("s_waitcnt vmcnt(0)" ::: "memory");
    __builtin_amdgcn_sched_barrier(0);
  }
  if constexpr (BAR) __builtin_amdgcn_s_barrier();
}

// MODE 0: A=xb[T,D] gathered by rid>>1; B LDS rows 0..127 = u rows
//         (yb*128..+128), rows 128..255 = g rows (HDIM + same range). Each
//         wave owns 32 output cols: acc[.][0..1]=u, acc[.][2..3]=g -> fused
//         silu epilogue in-register (no LDS exchange) -> act[rid][HDIM] bf16.
// MODE 1: A=act[T*K,H] by rid; B=w2b; epilogue pairs[rid][D] = acc*wts (f32).
template <int MODE>
__global__ __launch_bounds__(512, 2) void moe_gemm(
    const u16* __restrict__ A, const u16* __restrict__ Bw,
    const float* __restrict__ wts, const int* __restrict__ perm,
    const int* __restrict__ cnt, const int* __restrict__ tmap,
    const int* __restrict__ ntp, u16* __restrict__ act,
    float* __restrict__ pairs) {
  constexpr int KD = (MODE == 0) ? DMODEL : HDIM;
  constexpr int NT = KD / BK; // 64 / 44
  extern __shared__ char smem[];
  int* rid_s = (int*)(smem + 131072);

  if ((int)blockIdx.x >= *ntp) return;
  const int tm = tmap[blockIdx.x];
  const int e = tm >> 16, r0 = tm & 0xFFFF;
  const int ne = cnt[e];
  const int tid = threadIdx.x;
  if (tid < BM) {
    int ii = r0 + tid;
    rid_s[tid] = perm[e * T_TOK + (ii < ne ? ii : ne - 1)];
  }
  __syncthreads();

  const int w = tid >> 6, l = tid & 63;
  const int wr = w >> 2, wc = w & 3;
  const int yb = blockIdx.y;

  // ---- staging: wave w owns A chunks {2w,2w+1} and B chunks {2w,2w+1}
  // chunk c = 16 rows; lane l -> row 16c + (l>>2), slot l&3.
  // global source slot = (l&3) ^ ((row>>1)&3) = (l&3) ^ ((l>>3)&3).
  const int ar1 = 32 * w + (l >> 2);
  const int ar2 = ar1 + 16;
  const int sslot = ((l & 3) ^ ((l >> 3) & 3)) * 8; // element offset
  long arow1, arow2;
  {
    int rid1 = rid_s[ar1], rid2 = rid_s[ar2];
    arow1 = (MODE == 0) ? (rid1 >> 1) : rid1;
    arow2 = (MODE == 0) ? (rid2 >> 1) : rid2;
  }
  const u16* aptr1 = A + arow1 * KD + sslot;
  const u16* aptr2 = A + arow2 * KD + sslot;
  long brow1, brow2;
  if constexpr (MODE == 0) {
    brow1 = (long)e * (2 * HDIM) + (ar1 < 128 ? yb * 128 + ar1 : HDIM + yb * 128 + ar1 - 128);
    brow2 = (long)e * (2 * HDIM) + (ar2 < 128 ? yb * 128 + ar2 : HDIM + yb * 128 + ar2 - 128);
  } else {
    brow1 = (long)e * DMODEL + yb * BN + ar1;
    brow2 = (long)e * DMODEL + yb * BN + ar2;
  }
  const u16* bptr1 = Bw + brow1 * KD + sslot;
  const u16* bptr2 = Bw + brow2 * KD + sslot;
  const int aoffL1 = 2 * w * 1024, aoffL2 = aoffL1 + 1024;
  const int boffL1 = 16384 + 2 * w * 1024, boffL2 = boffL1 + 1024;

  // ---- ds_read fragment offsets (swizzled): k-slot (l>>4) ^ ((row>>1)&3)
  const int swz = ((l >> 4) ^ ((l >> 1) & 3)) * 16;
  int aoffR[8];
#pragma unroll
  for (int m = 0; m < 8; ++m)
    aoffR[m] = (wr * 128 + m * 16 + (l & 15)) * 64 + swz;
  int boffR[4];
#pragma unroll
  for (int n = 0; n < 4; ++n) {
    int br;
    if constexpr (MODE == 0)
      br = (n < 2) ? (wc * 32 + n * 16 + (l & 15)) : (128 + wc * 32 + (n - 2) * 16 + (l & 15));
    else
      br = wc * 64 + n * 16 + (l & 15);
    boffR[n] = 16384 + br * 64 + swz;
  }

  f32x4 acc[8][4] = {};

  // ---- prologue: stage tiles 0,1,2
#pragma unroll
  for (int tt = 0; tt < 3; ++tt) {
    char* sb = smem + tt * 32768;
    const size_t kq = (size_t)tt * BK;
    gll16(aptr1 + kq, sb + aoffL1);
    gll16(aptr2 + kq, sb + aoffL2);
    gll16(bptr1 + kq, sb + boffL1);
    gll16(bptr2 + kq, sb + boffL2);
  }
  asm volatile("s_waitcnt vmcnt(8)" ::: "memory"); // tile 0 landed
  __builtin_amdgcn_sched_barrier(0);
  __builtin_amdgcn_s_barrier();

  // ---- main loop: tiles 0..NT-4, staging tile t+3
  for (int t = 0; t <= NT - 4; ++t)
    ktile<8, true, true>(smem + (t & 3) * 32768, smem + ((t + 3) & 3) * 32768,
                         (size_t)(t + 3) * BK, aptr1, aptr2, bptr1, bptr2,
                         aoffL1, aoffL2, boffL1, boffL2, aoffR, boffR, acc);
  // ---- tail: tiles NT-3, NT-2, NT-1 (no staging; decreasing waits)
  ktile<4, false, true>(smem + ((NT - 3) & 3) * 32768, nullptr, 0,
                        aptr1, aptr2, bptr1, bptr2,
                        aoffL1, aoffL2, boffL1, boffL2, aoffR, boffR, acc);
  ktile<0, false, true>(smem + ((NT - 2) & 3) * 32768, nullptr, 0,
                        aptr1, aptr2, bptr1, bptr2,
                        aoffL1, aoffL2, boffL1, boffL2, aoffR, boffR, acc);
  ktile<-1, false, false>(smem + ((NT - 1) & 3) * 32768, nullptr, 0,
                          aptr1, aptr2, bptr1, bptr2,
                          aoffL1, aoffL2, boffL1, boffL2, aoffR, boffR, acc);

  // ---- epilogue. C/D layout: col = lane&15 (B-row), row = (lane>>4)*4+reg.
  if constexpr (MODE == 0) {
#pragma unroll
    for (int mm = 0; mm < 8; ++mm) {
      const int rb = wr * 128 + mm * 16 + (l >> 4) * 4;
#pragma unroll
      for (int rg = 0; rg < 4; ++rg) {
        const int rloc = rb + rg;
        if (r0 + rloc >= ne) continue;
        const int rid = rid_s[rloc];
#pragma unroll
        for (int n = 0; n < 2; ++n) {
          const int col = yb * 128 + wc * 32 + n * 16 + (l & 15);
          float u = acc[mm][n][rg];
          float g = acc[mm][n + 2][rg];
          float val = u * (g / (1.f + __expf(-g)));
          act[(size_t)rid * HDIM + col] = f2bf(val);
        }
      }
    }
  } else {
#pragma unroll
    for (int mm = 0; mm < 8; ++mm) {
      const int rb = wr * 128 + mm * 16 + (l >> 4) * 4;
#pragma unroll
      for (int rg = 0; rg < 4; ++rg) {
        const int rloc = rb + rg;
        if (r0 + rloc >= ne) continue;
        const int rid = rid_s[rloc];
        const float wt = wts[rid];
#pragma unroll
        for (int n = 0; n < 4; ++n) {
          const int col = yb * BN + wc * 64 + n * 16 + (l & 15);
          pairs[(size_t)rid * DMODEL + col] = acc[mm][n][rg] * wt;
        }
      }
    }
  }
}

// ---- y[t] = pairs[2t] + pairs[2t+1] ----
__global__ __launch_bounds__(256) void reduce_pairs(const float* __restrict__ pairs,
                                                    float* __restrict__ y) {
  const long total = (long)T_TOK * DMODEL / 4;
  const long stride = (long)gridDim.x * blockDim.x;
  for (long i = blockIdx.x * (long)blockDim.x + threadIdx.x; i < total; i += stride) {
    long t = (i * 4) / DMODEL;
    long d = (i * 4) % DMODEL;
    float4 a = *(const float4*)(pairs + (2 * t) * DMODEL + d);
    float4 b = *(const float4*)(pairs + (2 * t + 1) * DMODEL + d);
    float4 r;
    r.x = a.x + b.x; r.y = a.y + b.y; r.z = a.z + b.z; r.w = a.w + b.w;
    *(float4*)(y + t * DMODEL + d) = r;
  }
}

extern "C" void kernel_launch(void* const* d_in, const int* in_sizes, int n_in,
                              void* d_out, int out_size, void* d_ws, size_t ws_size,
                              hipStream_t stream) {
  const float* x = (const float*)d_in[0];
  const float* wts = (const float*)d_in[1];
  const int* idx = (const int*)d_in[2];
  const float* w1 = (const float*)d_in[3];
  const float* w2 = (const float*)d_in[4];
  float* y = (float*)d_out;

  char* ws = (char*)d_ws;
  size_t off = 0;
  int* cnt = (int*)(ws + off); off += 256;
  int* ntp = (int*)(ws + off); off += 256;
  int* tmap = (int*)(ws + off); off += 1024;
  int* perm = (int*)(ws + off); off += (size_t)NEXP * T_TOK * 4;
  off = (off + 255) & ~(size_t)255;
  size_t xb_off = off;
  u16* xb = (u16*)(ws + off);  off += (size_t)T_TOK * DMODEL * 2;             // 16.8 MB
  u16* w1b = (u16*)(ws + off); off += (size_t)NEXP * 2 * HDIM * DMODEL * 2;   // 92.3 MB
  u16* w2b = (u16*)(ws + off); off += (size_t)NEXP * DMODEL * HDIM * 2;       // 46.1 MB
  u16* act = (u16*)(ws + off); off += (size_t)T_TOK * TOPK * HDIM * 2;        // 23.1 MB
  // pairs aliases xb+w1b (both dead once GEMM1 finished): 67.1 MB <= 109 MB
  float* pairs = (float*)(ws + xb_off);

  (void)hipFuncSetAttribute((const void*)moe_gemm<0>,
                            hipFuncAttributeMaxDynamicSharedMemorySize, SMEM_BYTES);
  (void)hipFuncSetAttribute((const void*)moe_gemm<1>,
                            hipFuncAttributeMaxDynamicSharedMemorySize, SMEM_BYTES);

  hipMemsetAsync(cnt, 0, 256, stream);
  convert_k<<<2048, 256, 0, stream>>>(x, xb, (long)T_TOK * DMODEL / 8);
  convert_k<<<2048, 256, 0, stream>>>(w1, w1b, (long)NEXP * 2 * HDIM * DMODEL / 8);
  convert_k<<<2048, 256, 0, stream>>>(w2, w2b, (long)NEXP * DMODEL * HDIM / 8);
  route_kernel<<<(T_TOK * TOPK + 255) / 256, 256, 0, stream>>>(idx, cnt, perm);
  tilemap_kernel<<<1, 64, 0, stream>>>(cnt, tmap, ntp);
  moe_gemm<0><<<dim3(MAX_TILES, HDIM / 128), 512, SMEM_BYTES, stream>>>(
      xb, w1b, wts, perm, cnt, tmap, ntp, act, nullptr);
  moe_gemm<1><<<dim3(MAX_TILES, DMODEL / BN), 512, SMEM_BYTES, stream>>>(
      act, w2b, wts, perm, cnt, tmap, ntp, nullptr, pairs);
  reduce_pairs<<<2048, 256, 0, stream>>>(pairs, y);
}